// Round 11
// baseline (90.130 us; speedup 1.0000x reference)
//
#include <hip/hip_runtime.h>

// 5x5 box filter, zero pad, fp32, 8192x8192.
// R1/R4: register streaming, latency-bound: 168us.
// R2/R3: __launch_bounds__ min-waves cap => scratch-spill catastrophe. Never cap.
// R5: LDS tile sync staging: 116us. R6: async gll + TR=16 (7 blk/CU): 102.5us.
// R7: TR=32 TPB=256 (16 waves/CU): 110.8us. R8: ring pipeline: 118.5us (vmcnt drain).
// R9: + nontemporal stores (keep L2/L3 for input): 90.0us.
// R10: TR=8 (8 blk/CU, 32 waves/CU): 87.9us. Occupancy >> halo.
// R11: TPB=512, TR=32: 4 blk x 8 waves = 32 waves/CU AND halo 1.125x
//      (needs VGPR<=64, LDS 4x38016=152KB fits).

constexpr int H = 8192, W = 8192;
constexpr int TPB = 512;
constexpr int TC  = 256;            // output tile cols
constexpr int TR  = 32;             // output tile rows
constexpr int LR  = TR + 4;         // 36 staged rows
constexpr int LCF = TC + 8;         // 264 staged floats per row (pitch 1056 B)
constexpr int NCHUNK = LCF / 4;     // 66 f4 chunks per row
constexpr int TOTCH  = LR * NCHUNK; // 2376 chunks per tile

typedef float f4 __attribute__((ext_vector_type(4)));

#if defined(__has_builtin)
#  if __has_builtin(__builtin_amdgcn_global_load_lds)
#    define HAS_GLL 1
#  else
#    define HAS_GLL 0
#  endif
#else
#  define HAS_GLL 0
#endif

#if HAS_GLL
__device__ __forceinline__ void gload_lds16(const float* g, float* l) {
    __builtin_amdgcn_global_load_lds(
        (const __attribute__((address_space(1))) void*)g,
        (__attribute__((address_space(3))) void*)l,
        16, 0, 0);
}
#endif

__global__ __launch_bounds__(TPB)
void box5_kernel(const float* __restrict__ in, float* __restrict__ out) {
    __shared__ float lds[LR * LCF];          // 38016 B -> 4 blocks/CU (= 32 waves)
    const int cb  = blockIdx.x * TC;
    const int rb  = blockIdx.y * TR;
    const int tid = threadIdx.x;

    // Interior: every staged address (rows rb-2..rb+33, cols cb-4..cb+259) in-bounds.
    const bool interior = (blockIdx.x > 0) && (blockIdx.x < gridDim.x - 1) &&
                          (blockIdx.y > 0) && (blockIdx.y < gridDim.y - 1);

    // ---- Phase 1: stage 36x264 floats ----
    if (interior) {
#if HAS_GLL
        // Async direct-to-LDS: linear dest (chunk lin -> lds byte lin*16),
        // per-wave base + lane*16 -- exactly global_load_lds's dest form.
        #pragma unroll
        for (int it = 0; it < (TOTCH + TPB - 1) / TPB; ++it) {
            const int lin = tid + it * TPB;
            if (it < TOTCH / TPB || lin < TOTCH) {
                const int lr = lin / NCHUNK;
                const int lc = lin - lr * NCHUNK;
                const float* gp = in + (size_t)(rb - 2 + lr) * W + (cb - 4) + lc * 4;
                gload_lds16(gp, &lds[lin * 4]);
            }
        }
#else
        #pragma unroll
        for (int it = 0; it < (TOTCH + TPB - 1) / TPB; ++it) {
            const int lin = tid + it * TPB;
            if (it < TOTCH / TPB || lin < TOTCH) {
                const int lr = lin / NCHUNK;
                const int lc = lin - lr * NCHUNK;
                f4 v = *(const f4*)(in + (size_t)(rb - 2 + lr) * W + (cb - 4) + lc * 4);
                *(f4*)(&lds[lin * 4]) = v;
            }
        }
#endif
    } else {
        // Border blocks: predicated VGPR path with zero-fill.
        #pragma unroll
        for (int it = 0; it < (TOTCH + TPB - 1) / TPB; ++it) {
            const int lin = tid + it * TPB;
            if (it < TOTCH / TPB || lin < TOTCH) {
                const int lr = lin / NCHUNK;
                const int lc = lin - lr * NCHUNK;
                const int gr = rb - 2 + lr;
                const int gc = cb - 4 + lc * 4;
                f4 v = {0.f, 0.f, 0.f, 0.f};
                if ((unsigned)gr < (unsigned)H && (unsigned)gc < (unsigned)W)
                    v = *(const f4*)(in + (size_t)gr * W + gc);
                *(f4*)(&lds[lin * 4]) = v;
            }
        }
    }
    __syncthreads();

    // ---- Phase 2: horizontal 5-sums from LDS + vertical register ring ----
    const int lx = tid & 63;                 // 64 column groups (4 floats each)
    const int ly = tid >> 6;                 // 8 row sub-bands (4 rows each)
    const int colf = lx * 4;
    const int o0 = ly * 4;

    float h[5][4];                           // ring of horizontal 5-sums
    auto hrow = [&](int lraw, float* hh) {
        const float* p = &lds[lraw * LCF + colf];
        f4 A = *(const f4*)(p);              // 16B lane stride -> conflict-free
        f4 B = *(const f4*)(p + 4);
        f4 C = *(const f4*)(p + 8);
        hh[0] = ((A[2] + A[3]) + (B[0] + B[1])) + B[2];
        hh[1] = ((A[3] + B[0]) + (B[1] + B[2])) + B[3];
        hh[2] = ((B[0] + B[1]) + (B[2] + B[3])) + C[0];
        hh[3] = ((B[1] + B[2]) + (B[3] + C[0])) + C[1];
    };

    #pragma unroll
    for (int k = 0; k < 4; ++k) hrow(o0 + k, h[k]);

    const float inv25 = 1.0f / 25.0f;
    float* outp = out + (size_t)(rb + o0) * W + cb + colf;

    #pragma unroll
    for (int i = 0; i < 4; ++i) {
        hrow(o0 + i + 4, h[(i + 4) % 5]);    // compile-time ring index
        f4 ov;
        #pragma unroll
        for (int j = 0; j < 4; ++j)
            ov[j] = (((h[0][j] + h[1][j]) + (h[2][j] + h[3][j])) + h[4][j]) * inv25;
        // Output never re-read; wave-contiguous 1024B = full lines (no RMW).
        __builtin_nontemporal_store(ov, (f4*)(outp));
        outp += W;
    }
}

extern "C" void kernel_launch(void* const* d_in, const int* in_sizes, int n_in,
                              void* d_out, int out_size, void* d_ws, size_t ws_size,
                              hipStream_t stream) {
    const float* in = (const float*)d_in[0];
    // d_in[1] is the uniform 5x5 kernel = ones/25; folded into inv25.
    float* out = (float*)d_out;
    dim3 grid(W / TC, H / TR);               // (32, 256) = 8192 blocks
    box5_kernel<<<grid, dim3(TPB), 0, stream>>>(in, out);
}

// Round 12
// 88.206 us; speedup vs baseline: 1.0218x; 1.0218x over previous
//
#include <hip/hip_runtime.h>

// 5x5 box filter, zero pad, fp32, 8192x8192.
// R1/R4: register streaming, latency-bound: 168us.
// R2/R3: __launch_bounds__ min-waves cap => scratch-spill catastrophe. Never cap.
// R5: LDS tile sync staging: 116us. R6: async gll + TR=16 (7 blk/CU): 102.5us.
// R7: TR=32 TPB=256 (16 waves/CU): 110.8us. R8: ring pipeline: 118.5us (vmcnt drain).
// R9: + nontemporal stores (keep L2/L3 for input): 90.0us.
// R10: TR=8 (8 blk/CU, 32 waves/CU): 87.9us. Occupancy >> halo (halo is L2-served).
// R11: TPB=512/TR=32 (32 waves, 1.125x halo): 90.1us -- halo saving bought nothing
//      (already cache-served); bigger stage quantum cost ~2us. REVERT to R10.
// Final: 87.9us ~= 103% of the 85us mixed-stream floor (512MiB @ 6.3TB/s).

constexpr int H = 8192, W = 8192;
constexpr int TPB = 256;
constexpr int TC  = 256;            // output tile cols
constexpr int TR  = 8;              // output tile rows
constexpr int LR  = TR + 4;         // 12 staged rows
constexpr int LCF = TC + 8;         // 264 staged floats per row (pitch 1056 B)
constexpr int NCHUNK = LCF / 4;     // 66 f4 chunks per row
constexpr int TOTCH  = LR * NCHUNK; // 792 chunks per tile

typedef float f4 __attribute__((ext_vector_type(4)));

#if defined(__has_builtin)
#  if __has_builtin(__builtin_amdgcn_global_load_lds)
#    define HAS_GLL 1
#  else
#    define HAS_GLL 0
#  endif
#else
#  define HAS_GLL 0
#endif

#if HAS_GLL
__device__ __forceinline__ void gload_lds16(const float* g, float* l) {
    __builtin_amdgcn_global_load_lds(
        (const __attribute__((address_space(1))) void*)g,
        (__attribute__((address_space(3))) void*)l,
        16, 0, 0);
}
#endif

__global__ __launch_bounds__(TPB)
void box5_kernel(const float* __restrict__ in, float* __restrict__ out) {
    __shared__ float lds[LR * LCF];          // 12672 B -> 8 blocks/CU (wave-slot cap)
    const int cb  = blockIdx.x * TC;
    const int rb  = blockIdx.y * TR;
    const int tid = threadIdx.x;

    // Interior: every staged address (rows rb-2..rb+9, cols cb-4..cb+259) in-bounds.
    const bool interior = (blockIdx.x > 0) && (blockIdx.x < gridDim.x - 1) &&
                          (blockIdx.y > 0) && (blockIdx.y < gridDim.y - 1);

    // ---- Phase 1: stage 12x264 floats ----
    if (interior) {
#if HAS_GLL
        // Async direct-to-LDS: linear dest (chunk lin -> lds byte lin*16),
        // wave-uniform base + lane*16 -- exactly global_load_lds's dest form.
        #pragma unroll
        for (int it = 0; it < (TOTCH + TPB - 1) / TPB; ++it) {
            const int lin = tid + it * TPB;
            if (it < TOTCH / TPB || lin < TOTCH) {
                const int lr = lin / NCHUNK;
                const int lc = lin - lr * NCHUNK;
                const float* gp = in + (size_t)(rb - 2 + lr) * W + (cb - 4) + lc * 4;
                gload_lds16(gp, &lds[lin * 4]);
            }
        }
#else
        #pragma unroll
        for (int it = 0; it < (TOTCH + TPB - 1) / TPB; ++it) {
            const int lin = tid + it * TPB;
            if (it < TOTCH / TPB || lin < TOTCH) {
                const int lr = lin / NCHUNK;
                const int lc = lin - lr * NCHUNK;
                f4 v = *(const f4*)(in + (size_t)(rb - 2 + lr) * W + (cb - 4) + lc * 4);
                *(f4*)(&lds[lin * 4]) = v;
            }
        }
#endif
    } else {
        // Border blocks: predicated VGPR path with zero-fill.
        #pragma unroll
        for (int it = 0; it < (TOTCH + TPB - 1) / TPB; ++it) {
            const int lin = tid + it * TPB;
            if (it < TOTCH / TPB || lin < TOTCH) {
                const int lr = lin / NCHUNK;
                const int lc = lin - lr * NCHUNK;
                const int gr = rb - 2 + lr;
                const int gc = cb - 4 + lc * 4;
                f4 v = {0.f, 0.f, 0.f, 0.f};
                if ((unsigned)gr < (unsigned)H && (unsigned)gc < (unsigned)W)
                    v = *(const f4*)(in + (size_t)gr * W + gc);
                *(f4*)(&lds[lin * 4]) = v;
            }
        }
    }
    __syncthreads();

    // ---- Phase 2: horizontal 5-sums from LDS + vertical register ring ----
    const int lx = tid & 63;                 // 64 column groups (4 floats each)
    const int ly = tid >> 6;                 // 4 row sub-bands (2 rows each)
    const int colf = lx * 4;
    const int o0 = ly * 2;

    float h[5][4];                           // ring of horizontal 5-sums
    auto hrow = [&](int lraw, float* hh) {
        const float* p = &lds[lraw * LCF + colf];
        f4 A = *(const f4*)(p);              // 16B lane stride -> conflict-free
        f4 B = *(const f4*)(p + 4);
        f4 C = *(const f4*)(p + 8);
        hh[0] = ((A[2] + A[3]) + (B[0] + B[1])) + B[2];
        hh[1] = ((A[3] + B[0]) + (B[1] + B[2])) + B[3];
        hh[2] = ((B[0] + B[1]) + (B[2] + B[3])) + C[0];
        hh[3] = ((B[1] + B[2]) + (B[3] + C[0])) + C[1];
    };

    #pragma unroll
    for (int k = 0; k < 4; ++k) hrow(o0 + k, h[k]);

    const float inv25 = 1.0f / 25.0f;
    float* outp = out + (size_t)(rb + o0) * W + cb + colf;

    #pragma unroll
    for (int i = 0; i < 2; ++i) {
        hrow(o0 + i + 4, h[(i + 4) % 5]);    // compile-time ring index
        f4 ov;
        #pragma unroll
        for (int j = 0; j < 4; ++j)
            ov[j] = (((h[0][j] + h[1][j]) + (h[2][j] + h[3][j])) + h[4][j]) * inv25;
        // Output never re-read; wave-contiguous 1024B = full lines (no RMW).
        __builtin_nontemporal_store(ov, (f4*)(outp));
        outp += W;
    }
}

extern "C" void kernel_launch(void* const* d_in, const int* in_sizes, int n_in,
                              void* d_out, int out_size, void* d_ws, size_t ws_size,
                              hipStream_t stream) {
    const float* in = (const float*)d_in[0];
    // d_in[1] is the uniform 5x5 kernel = ones/25; folded into inv25.
    float* out = (float*)d_out;
    dim3 grid(W / TC, H / TR);               // (32, 1024) = 32768 blocks
    box5_kernel<<<grid, dim3(TPB), 0, stream>>>(in, out);
}